// Round 4
// baseline (62.668 us; speedup 1.0000x reference)
//
#include <hip/hip_runtime.h>
#include <cstdint>

#define NTOK 16384

typedef float f4 __attribute__((ext_vector_type(4)));

__device__ __forceinline__ float readlane_f(float v, int lane) {
  return __int_as_float(__builtin_amdgcn_readlane(__float_as_int(v), lane));
}

__device__ __forceinline__ float wave_sum64(float v) {
  #pragma unroll
  for (int s = 1; s < 64; s <<= 1) v += __shfl_xor(v, s, 64);
  return v;
}

__device__ __forceinline__ float half_sum32(float v) {
  // independent sums within lanes 0-31 and 32-63
  #pragma unroll
  for (int s = 1; s < 32; s <<= 1) v += __shfl_xor(v, s, 64);
  return v;
}

__device__ __forceinline__ float elemf(f4 v, int e) {
  return e == 0 ? v.x : e == 1 ? v.y : e == 2 ? v.z : v.w;
}

// ---------------------------------------------------------------------------
// Fused mLSTM, software-pipelined: one 512-thread block per CU, 8 waves,
// 8 tokens per wave processed as 4 groups of 2:
//   loop g: { project 2 tokens (LDS bf16 weights) -> expand+store 2 tokens }
// Stores start ~2.5us into the kernel (vs ~9us with the monolithic phase A),
// and per-group VALU hides under the previous group's HBM store drain.
//  n = f*n_prev + i*k
//  h = o * (f*(c_prev@q) + i*v*(k.q)) / max(|n.q|,1)   (c_t never re-read)
//  c = f*c_prev + i*outer(v,k)   -> 16 x dwordx4 per token, contiguous 1KB/instr
// ---------------------------------------------------------------------------
__global__ void __launch_bounds__(512, 2)
fused_kernel(const float* __restrict__ x,
             const float* __restrict__ c_prev,
             const float* __restrict__ n_prev,
             const float* __restrict__ w_q, const float* __restrict__ b_q,
             const float* __restrict__ w_k, const float* __restrict__ b_k,
             const float* __restrict__ w_v, const float* __restrict__ b_v,
             const float* __restrict__ w_i, const float* __restrict__ b_i,
             const float* __restrict__ w_f, const float* __restrict__ b_f,
             const float* __restrict__ w_o, const float* __restrict__ b_o,
             float* __restrict__ h_out,
             float* __restrict__ c_out,
             float* __restrict__ n_out)
{
  __shared__ uint32_t wlds[4][64][64];   // 64 KB: bf16-pair-packed weights
  __shared__ float    cp[64][68];        // 17 KB: c_prev, padded stride
  const int tid = threadIdx.x;

  {
    const float* Ws[4] = {w_q, w_k, w_v, w_o};
    #pragma unroll
    for (int m = 0; m < 4; ++m) {
      const float* W = Ws[m];
      #pragma unroll
      for (int it = 0; it < 8; ++it) {
        int idx = it * 512 + tid;      // 0..4095
        int dp  = idx >> 6;            // d-pair 0..63
        int j   = idx & 63;            // output column
        uint32_t ua = __float_as_uint(W[(2 * dp)     * 64 + j]);
        uint32_t ub = __float_as_uint(W[(2 * dp + 1) * 64 + j]);
        ua = (ua + 0x7FFFu + ((ua >> 16) & 1u)) >> 16;   // rne bf16
        ub = (ub + 0x7FFFu + ((ub >> 16) & 1u)) >> 16;
        wlds[m][j][dp ^ ((j & 7) << 2)] = (ua & 0xFFFFu) | (ub << 16);
      }
    }
  }
  for (int idx = tid; idx < 4096; idx += 512)
    cp[idx >> 6][idx & 63] = c_prev[idx];
  __syncthreads();

  const int lane = tid & 63;
  const int wid  = tid >> 6;
  const int t0   = blockIdx.x * 64 + wid * 8;    // 8 tokens per wave

  const float bq = b_q[lane], bk = b_k[lane], bv = b_v[lane], bo = b_o[lane];
  const float npv = n_prev[lane];
  const int   m   = lane & 15;
  const int   dbase = (lane & 31) << 2;
  const f4 wi4 = *(const f4*)&w_i[dbase];
  const f4 wf4 = *(const f4*)&w_f[dbase];
  const float sbi = b_i[0], sbf = b_f[0];

  // x chunk for group g: flat floats [256g..256g+255] of x[t0..t0+7][*];
  // lane l holds x[t0+2g+(l>>5)][4*(l&31)+e] in element e.
  const f4* xp = (const f4*)(x + (size_t)t0 * 128);
  f4 xg = xp[lane];                              // group 0 chunk

  #pragma unroll 1
  for (int g = 0; g < 4; ++g) {
    const f4 xnext = xp[((g + 1) & 3) * 64 + lane];   // prefetch next chunk

    // ---- phase A: project tokens t0+2g, t0+2g+1 ----
    float aq[2], ak[2], av[2], ao[2];
    aq[0] = aq[1] = bq; ak[0] = ak[1] = bk;
    av[0] = av[1] = bv; ao[0] = ao[1] = bo;

    #pragma unroll 2
    for (int dp4 = 0; dp4 < 16; ++dp4) {
      const int off = (dp4 * 4) ^ ((lane & 7) << 2);
      const uint4 uq = *(const uint4*)&wlds[0][lane][off];
      const uint4 uk = *(const uint4*)&wlds[1][lane][off];
      const uint4 uv = *(const uint4*)&wlds[2][lane][off];
      const uint4 uo = *(const uint4*)&wlds[3][lane][off];
      #pragma unroll
      for (int e = 0; e < 4; ++e) {
        const uint32_t cq = (&uq.x)[e], ck = (&uk.x)[e];
        const uint32_t cv = (&uv.x)[e], co = (&uo.x)[e];
        const float wq0 = __uint_as_float(cq << 16), wq1 = __uint_as_float(cq & 0xFFFF0000u);
        const float wk0 = __uint_as_float(ck << 16), wk1 = __uint_as_float(ck & 0xFFFF0000u);
        const float wv0 = __uint_as_float(cv << 16), wv1 = __uint_as_float(cv & 0xFFFF0000u);
        const float wo0 = __uint_as_float(co << 16), wo1 = __uint_as_float(co & 0xFFFF0000u);
        const int lsub = 2 * dp4 + (e >> 1);           // (dp4*8+2e)>>2, uniform
        #pragma unroll
        for (int tt = 0; tt < 2; ++tt) {
          const int lidx = (tt << 5) + lsub;
          const float xa = readlane_f(elemf(xg, (2 * e) & 3), lidx);
          const float xb = readlane_f(elemf(xg, (2 * e + 1) & 3), lidx);
          aq[tt] = fmaf(wq0, xa, aq[tt]); aq[tt] = fmaf(wq1, xb, aq[tt]);
          ak[tt] = fmaf(wk0, xa, ak[tt]); ak[tt] = fmaf(wk1, xb, ak[tt]);
          av[tt] = fmaf(wv0, xa, av[tt]); av[tt] = fmaf(wv1, xb, av[tt]);
          ao[tt] = fmaf(wo0, xa, ao[tt]); ao[tt] = fmaf(wo1, xb, ao[tt]);
        }
      }
    }

    // gates in full f32 from xg
    float it01[2], ft01[2];
    {
      float pi = xg.x * wi4.x + xg.y * wi4.y + xg.z * wi4.z + xg.w * wi4.w;
      float pf = xg.x * wf4.x + xg.y * wf4.y + xg.z * wf4.z + xg.w * wf4.w;
      pi = half_sum32(pi);
      pf = half_sum32(pf);
      it01[0] = __expf(readlane_f(pi, 0)  + sbi);
      it01[1] = __expf(readlane_f(pi, 32) + sbi);
      ft01[0] = 1.0f / (1.0f + __expf(-(readlane_f(pf, 0)  + sbf)));
      ft01[1] = 1.0f / (1.0f + __expf(-(readlane_f(pf, 32) + sbf)));
    }

    // ---- phase B: expand + store tokens ----
    #pragma unroll
    for (int tt = 0; tt < 2; ++tt) {
      const size_t t = (size_t)(t0 + 2 * g + tt);
      const float q   = aq[tt];
      const float k   = ak[tt] * 0.125f;             // 1/sqrt(64)
      const float v   = av[tt];
      const float o   = 1.0f / (1.0f + __expf(-ao[tt]));
      const float it_ = it01[tt];
      const float ft_ = ft01[tt];

      const float n_val = fmaf(ft_, npv, it_ * k);
      n_out[t * 64 + lane] = n_val;

      const float nq = wave_sum64(n_val * q);
      const float kq = wave_sum64(k * q);

      float c0 = 0.f, c1 = 0.f, c2 = 0.f, c3 = 0.f;
      #pragma unroll
      for (int j = 0; j < 16; ++j) {
        const f4 r4 = *(const f4*)&cp[lane][4 * j];
        c0 = fmaf(r4.x, readlane_f(q, 4 * j),     c0);
        c1 = fmaf(r4.y, readlane_f(q, 4 * j + 1), c1);
        c2 = fmaf(r4.z, readlane_f(q, 4 * j + 2), c2);
        c3 = fmaf(r4.w, readlane_f(q, 4 * j + 3), c3);
      }
      const float cpq = (c0 + c1) + (c2 + c3);

      const float inv  = 1.0f / fmaxf(fabsf(nq), 1.0f);
      const float htil = fmaf(ft_, cpq, it_ * v * kq) * inv;
      h_out[t * 64 + lane] = o * htil;

      const float iv = it_ * v;
      const float k40 = __shfl(k, 4 * m, 64);
      const float k41 = __shfl(k, 4 * m + 1, 64);
      const float k42 = __shfl(k, 4 * m + 2, 64);
      const float k43 = __shfl(k, 4 * m + 3, 64);
      f4* ct = (f4*)(c_out + t * 4096);
      #pragma unroll
      for (int s = 0; s < 16; ++s) {
        const int row = 4 * s + (lane >> 4);
        const float ivr = __shfl(iv, row, 64);
        const f4 c4 = *(const f4*)&cp[row][4 * m];
        f4 val;
        val.x = fmaf(ft_, c4.x, ivr * k40);
        val.y = fmaf(ft_, c4.y, ivr * k41);
        val.z = fmaf(ft_, c4.z, ivr * k42);
        val.w = fmaf(ft_, c4.w, ivr * k43);
        ct[s * 64 + lane] = val;
      }
    }

    xg = xnext;
  }
}

extern "C" void kernel_launch(void* const* d_in, const int* in_sizes, int n_in,
                              void* d_out, int out_size, void* d_ws, size_t ws_size,
                              hipStream_t stream) {
  const float* x      = (const float*)d_in[0];
  const float* c_prev = (const float*)d_in[1];
  const float* n_prev = (const float*)d_in[2];
  const float* w_q = (const float*)d_in[3];
  const float* b_q = (const float*)d_in[4];
  const float* w_k = (const float*)d_in[5];
  const float* b_k = (const float*)d_in[6];
  const float* w_v = (const float*)d_in[7];
  const float* b_v = (const float*)d_in[8];
  const float* w_i = (const float*)d_in[9];
  const float* b_i = (const float*)d_in[10];
  const float* w_f = (const float*)d_in[11];
  const float* b_f = (const float*)d_in[12];
  const float* w_o = (const float*)d_in[13];
  const float* b_o = (const float*)d_in[14];

  float* h_out = (float*)d_out;               // 1,048,576
  float* c_out = h_out + 1048576;             // 67,108,864
  float* n_out = c_out + 67108864;            // 1,048,576

  fused_kernel<<<256, 512, 0, stream>>>(x, c_prev, n_prev,
                                        w_q, b_q, w_k, b_k, w_v, b_v,
                                        w_i, b_i, w_f, b_f, w_o, b_o,
                                        h_out, c_out, n_out);
}

// Round 5
// 55.658 us; speedup vs baseline: 1.1259x; 1.1259x over previous
//
#include <hip/hip_runtime.h>
#include <cstdint>

#define NTOK 16384

typedef float f4 __attribute__((ext_vector_type(4)));
typedef __attribute__((ext_vector_type(4))) float f32x4;
typedef __attribute__((ext_vector_type(8))) short bf16x8;

__device__ __forceinline__ float readlane_f(float v, int lane) {
  return __int_as_float(__builtin_amdgcn_readlane(__float_as_int(v), lane));
}

__device__ __forceinline__ float wave_sum64(float v) {
  #pragma unroll
  for (int s = 1; s < 64; s <<= 1) v += __shfl_xor(v, s, 64);
  return v;
}

__device__ __forceinline__ float half_sum32(float v) {
  #pragma unroll
  for (int s = 1; s < 32; s <<= 1) v += __shfl_xor(v, s, 64);
  return v;
}

__device__ __forceinline__ uint32_t rne_bf16(float f) {
  uint32_t u = __float_as_uint(f);
  return (u + 0x7FFFu + ((u >> 16) & 1u)) >> 16;   // round-nearest-even bf16
}

// ---------------------------------------------------------------------------
// Fused mLSTM, MFMA projections. Grid 256 x 512 threads (1 block/CU, 8 waves,
// 64 tokens/block, 8 per wave).
//  Stage:  wT[n=256][k=128] bf16, XOR-swizzled 16B units, in 64KB LDS.
//  PhaseA: Y[64x256] = X @ [wq|wk|wv|wo] via mfma_f32_16x16x32_bf16.
//          wave tile: m-tile (wid&3), 8 n-tiles ((wid>>2)*8..+7), 4 k-steps.
//          After barrier, Y(f32) overwrites the dead weight LDS (exact 64KB).
//  Gates:  i/f in full f32 from per-wave xc chunks (R3-proven path).
//  PhaseB: per token (R3-proven):
//          n = f*n_prev + i*k
//          h = o * (f*(c_prev@q) + i*v*(k.q)) / max(|n.q|,1)
//          c = f*c_prev + i*outer(v,k) -> 16 x dwordx4, contiguous 1KB/instr
// ---------------------------------------------------------------------------
__global__ void __launch_bounds__(512, 2)
fused_kernel(const float* __restrict__ x,
             const float* __restrict__ c_prev,
             const float* __restrict__ n_prev,
             const float* __restrict__ w_q, const float* __restrict__ b_q,
             const float* __restrict__ w_k, const float* __restrict__ b_k,
             const float* __restrict__ w_v, const float* __restrict__ b_v,
             const float* __restrict__ w_i, const float* __restrict__ b_i,
             const float* __restrict__ w_f, const float* __restrict__ b_f,
             const float* __restrict__ w_o, const float* __restrict__ b_o,
             float* __restrict__ h_out,
             float* __restrict__ c_out,
             float* __restrict__ n_out)
{
  __shared__ uint32_t smem[16384];   // 64KB: wT bf16 (phase A) -> Y f32 (phase B)
  __shared__ float    cp[64][68];    // 17KB: c_prev, padded stride
  const int tid  = threadIdx.x;
  const int lane = tid & 63;
  const int wid  = tid >> 6;
  const int T0   = blockIdx.x * 64;

  // ---- stage wT[n][k] as bf16 pairs, unit-swizzled ----
  // unit(n, kb) = n*16 + (kb ^ (n&15)), kb = 16B-block along k (8 bf16)
  {
    const int n   = tid & 255;              // constant per thread
    const int col = n & 63;
    const float* W = (n < 128) ? ((n < 64) ? w_q : w_k)
                               : ((n < 192) ? w_v : w_o);
    const int kph = tid >> 8;               // 0 or 1
    #pragma unroll
    for (int it = 0; it < 32; ++it) {
      const int kp = it * 2 + kph;          // k-pair 0..63
      const float a = W[(2 * kp)     * 64 + col];
      const float b = W[(2 * kp + 1) * 64 + col];
      const uint32_t pk = rne_bf16(a) | (rne_bf16(b) << 16);
      const int unit = (n << 4) + ((kp >> 2) ^ (n & 15));
      smem[(unit << 2) + (kp & 3)] = pk;
    }
  }
  for (int idx = tid; idx < 4096; idx += 512)
    cp[idx >> 6][idx & 63] = c_prev[idx];

  // xc chunks for gates (independent of LDS; issue early)
  // lane l holds x[T0 + wid*8 + 2c + (l>>5)][4*(l&31)+e] in xc[c].e
  const f4* xp = (const f4*)(x + (size_t)(T0 + wid * 8) * 128);
  f4 xc[4];
  xc[0] = xp[lane];
  xc[1] = xp[64 + lane];
  xc[2] = xp[128 + lane];
  xc[3] = xp[192 + lane];

  __syncthreads();

  // ---- phase A: MFMA projections ----
  const int mt  = wid & 3;                  // m-tile (16 tokens)
  const int ntg = (wid >> 2) * 8;           // first of 8 n-tiles
  bf16x8 afrag[4];
  {
    const float* xr = x + (size_t)(T0 + mt * 16 + (lane & 15)) * 128
                        + ((lane >> 4) * 8);
    #pragma unroll
    for (int ks = 0; ks < 4; ++ks) {
      const f4 lo = *(const f4*)(xr + ks * 32);
      const f4 hi = *(const f4*)(xr + ks * 32 + 4);
      union { uint32_t u[4]; bf16x8 v; } cv;
      cv.u[0] = rne_bf16(lo.x) | (rne_bf16(lo.y) << 16);
      cv.u[1] = rne_bf16(lo.z) | (rne_bf16(lo.w) << 16);
      cv.u[2] = rne_bf16(hi.x) | (rne_bf16(hi.y) << 16);
      cv.u[3] = rne_bf16(hi.z) | (rne_bf16(hi.w) << 16);
      afrag[ks] = cv.v;
    }
  }
  f32x4 acc[8];
  #pragma unroll
  for (int j = 0; j < 8; ++j) acc[j] = (f32x4){0.f, 0.f, 0.f, 0.f};
  {
    const int bsub = lane & 15, bh = lane >> 4;
    #pragma unroll
    for (int nti = 0; nti < 8; ++nti) {
      const int n = (ntg + nti) * 16 + bsub;
      #pragma unroll
      for (int ks = 0; ks < 4; ++ks) {
        const int unit = (n << 4) + ((ks * 4 + bh) ^ (n & 15));
        const bf16x8 bfrag = *(const bf16x8*)&smem[unit << 2];
        acc[nti] = __builtin_amdgcn_mfma_f32_16x16x32_bf16(afrag[ks], bfrag,
                                                           acc[nti], 0, 0, 0);
      }
    }
  }
  __syncthreads();                          // all wT reads done; region dies
  {
    float* y = (float*)smem;                // Y[64][256] f32, exact 64KB
    const int trow = mt * 16 + (lane >> 4) * 4;
    const int fcol = lane & 15;
    #pragma unroll
    for (int nti = 0; nti < 8; ++nti) {
      const int f = (ntg + nti) * 16 + fcol;
      #pragma unroll
      for (int r = 0; r < 4; ++r)
        y[(trow + r) * 256 + f] = acc[nti][r];
    }
  }
  __syncthreads();

  // ---- gates in full f32 ----
  float itv[8], ftv[8];
  {
    const int dbase = (lane & 31) << 2;
    const f4 wi4 = *(const f4*)&w_i[dbase];
    const f4 wf4 = *(const f4*)&w_f[dbase];
    const float sbi = b_i[0], sbf = b_f[0];
    #pragma unroll
    for (int c = 0; c < 4; ++c) {
      float pi = xc[c].x * wi4.x + xc[c].y * wi4.y + xc[c].z * wi4.z + xc[c].w * wi4.w;
      float pf = xc[c].x * wf4.x + xc[c].y * wf4.y + xc[c].z * wf4.z + xc[c].w * wf4.w;
      pi = half_sum32(pi);
      pf = half_sum32(pf);
      itv[2 * c]     = __expf(readlane_f(pi, 0)  + sbi);
      itv[2 * c + 1] = __expf(readlane_f(pi, 32) + sbi);
      ftv[2 * c]     = 1.0f / (1.0f + __expf(-(readlane_f(pf, 0)  + sbf)));
      ftv[2 * c + 1] = 1.0f / (1.0f + __expf(-(readlane_f(pf, 32) + sbf)));
    }
  }

  // ---- phase B: expand + store ----
  const float bq = b_q[lane], bk = b_k[lane], bv = b_v[lane], bo = b_o[lane];
  const float npv = n_prev[lane];
  const int   m   = lane & 15;
  const float* y  = (const float*)smem;

  #pragma unroll 1
  for (int tt = 0; tt < 8; ++tt) {
    const int    tl = wid * 8 + tt;
    const size_t t  = (size_t)(T0 + tl);
    const float q   = y[tl * 256 + lane] + bq;
    const float k   = (y[tl * 256 + 64 + lane] + bk) * 0.125f;   // 1/sqrt(64)
    const float v   = y[tl * 256 + 128 + lane] + bv;
    const float o   = 1.0f / (1.0f + __expf(-(y[tl * 256 + 192 + lane] + bo)));
    const float it_ = itv[tt];
    const float ft_ = ftv[tt];

    const float n_val = fmaf(ft_, npv, it_ * k);
    n_out[t * 64 + lane] = n_val;

    const float nq = wave_sum64(n_val * q);
    const float kq = wave_sum64(k * q);

    float c0 = 0.f, c1 = 0.f, c2 = 0.f, c3 = 0.f;
    #pragma unroll
    for (int j = 0; j < 16; ++j) {
      const f4 r4 = *(const f4*)&cp[lane][4 * j];
      c0 = fmaf(r4.x, readlane_f(q, 4 * j),     c0);
      c1 = fmaf(r4.y, readlane_f(q, 4 * j + 1), c1);
      c2 = fmaf(r4.z, readlane_f(q, 4 * j + 2), c2);
      c3 = fmaf(r4.w, readlane_f(q, 4 * j + 3), c3);
    }
    const float cpq = (c0 + c1) + (c2 + c3);

    const float inv  = 1.0f / fmaxf(fabsf(nq), 1.0f);
    const float htil = fmaf(ft_, cpq, it_ * v * kq) * inv;
    h_out[t * 64 + lane] = o * htil;

    const float iv = it_ * v;
    const float k40 = __shfl(k, 4 * m, 64);
    const float k41 = __shfl(k, 4 * m + 1, 64);
    const float k42 = __shfl(k, 4 * m + 2, 64);
    const float k43 = __shfl(k, 4 * m + 3, 64);
    f4* ct = (f4*)(c_out + t * 4096);
    #pragma unroll
    for (int s = 0; s < 16; ++s) {
      const int row = 4 * s + (lane >> 4);
      const float ivr = __shfl(iv, row, 64);
      const f4 c4 = *(const f4*)&cp[row][4 * m];
      f4 val;
      val.x = fmaf(ft_, c4.x, ivr * k40);
      val.y = fmaf(ft_, c4.y, ivr * k41);
      val.z = fmaf(ft_, c4.z, ivr * k42);
      val.w = fmaf(ft_, c4.w, ivr * k43);
      ct[s * 64 + lane] = val;
    }
  }
}

extern "C" void kernel_launch(void* const* d_in, const int* in_sizes, int n_in,
                              void* d_out, int out_size, void* d_ws, size_t ws_size,
                              hipStream_t stream) {
  const float* x      = (const float*)d_in[0];
  const float* c_prev = (const float*)d_in[1];
  const float* n_prev = (const float*)d_in[2];
  const float* w_q = (const float*)d_in[3];
  const float* b_q = (const float*)d_in[4];
  const float* w_k = (const float*)d_in[5];
  const float* b_k = (const float*)d_in[6];
  const float* w_v = (const float*)d_in[7];
  const float* b_v = (const float*)d_in[8];
  const float* w_i = (const float*)d_in[9];
  const float* b_i = (const float*)d_in[10];
  const float* w_f = (const float*)d_in[11];
  const float* b_f = (const float*)d_in[12];
  const float* w_o = (const float*)d_in[13];
  const float* b_o = (const float*)d_in[14];

  float* h_out = (float*)d_out;               // 1,048,576
  float* c_out = h_out + 1048576;             // 67,108,864
  float* n_out = c_out + 67108864;            // 1,048,576

  fused_kernel<<<256, 512, 0, stream>>>(x, c_prev, n_prev,
                                        w_q, b_q, w_k, b_k, w_v, b_v,
                                        w_i, b_i, w_f, b_f, w_o, b_o,
                                        h_out, c_out, n_out);
}